// Round 3
// baseline (172.813 us; speedup 1.0000x reference)
//
#include <hip/hip_runtime.h>
#include <hip/hip_bf16.h>
#include <hip/hip_cooperative_groups.h>

namespace cg = cooperative_groups;

#define BATCH 16384
#define FIELDS 50
#define EMB 64
#define HID 200
#define NCOPY 16
#define GRID 512
#define RPB 32  // rows per block; GRID*RPB == BATCH

// One cooperative kernel, 5 phases:
//  P1 gather+FM -> sbi (LDS) + BN1 partial stats (atomics, NCOPY copies)
//  P2 BN1 coef finalize (redundant per block)
//  P3 relu(BN1(bi)) @ W1 + b1 -> registers (y never hits HBM) + BN2 stats
//  P4 BN2 coef finalize
//  P5 relu(BN2(y)) . w_last -> sigmoid -> out
// y layout trick: wave w's acc[r][k] holds y[row0+w*8+r][k*64+l], exactly the
// per-lane layout the 200-dim output dot needs. bi lives only in LDS.
__global__ __launch_bounds__(256, 2) void k_fused(
    const int* __restrict__ x, const float* __restrict__ emb,
    const float* __restrict__ w1, const float* __restrict__ b1,
    const float* __restrict__ wl, const float* __restrict__ bl,
    const float* __restrict__ g_bi, const float* __restrict__ be_bi,
    const float* __restrict__ g_h, const float* __restrict__ be_h,
    float* __restrict__ out, float* __restrict__ st1, float* __restrict__ st2)
{
    __shared__ int sidx[RPB * FIELDS];          // 6.4 KB
    __shared__ float sbi[RPB][EMB];             // 8 KB
    __shared__ float w1s[EMB * HID + 64];       // 51.5 KB (padded tail)
    __shared__ float b1s[HID];
    __shared__ float c1s[128];
    __shared__ float c2s[400];
    __shared__ float swave[4][128];

    const int tid = threadIdx.x;
    const int bid = blockIdx.x;
    const int row0 = bid * RPB;
    const int lane = tid & 63;
    const int w = tid >> 6;

    // ---------------- P1: gather + FM bi-interaction ----------------
    for (int i = tid; i < RPB * FIELDS; i += 256)
        sidx[i] = x[row0 * FIELDS + i];
    __syncthreads();

    const int r = tid >> 4;   // 0..15
    const int c = tid & 15;   // dims 4c..4c+3
    float pv0 = 0, pv1 = 0, pv2 = 0, pv3 = 0;
    float pq0 = 0, pq1 = 0, pq2 = 0, pq3 = 0;
#pragma unroll
    for (int g = 0; g < 2; ++g) {
        const int* rowidx = sidx + (g * 16 + r) * FIELDS;
        float s0 = 0, s1 = 0, s2 = 0, s3 = 0, q0 = 0, q1 = 0, q2 = 0, q3 = 0;
#pragma unroll 10
        for (int f = 0; f < FIELDS; ++f) {
            const float4 v = *(const float4*)(emb + (size_t)rowidx[f] * EMB + c * 4);
            s0 += v.x; q0 += v.x * v.x;
            s1 += v.y; q1 += v.y * v.y;
            s2 += v.z; q2 += v.z * v.z;
            s3 += v.w; q3 += v.w * v.w;
        }
        float4 o;
        o.x = 0.5f * (s0 * s0 - q0);
        o.y = 0.5f * (s1 * s1 - q1);
        o.z = 0.5f * (s2 * s2 - q2);
        o.w = 0.5f * (s3 * s3 - q3);
        *(float4*)(&sbi[g * 16 + r][c * 4]) = o;
        pv0 += o.x; pq0 += o.x * o.x;
        pv1 += o.y; pq1 += o.y * o.y;
        pv2 += o.z; pq2 += o.z * o.z;
        pv3 += o.w; pq3 += o.w * o.w;
    }
#pragma unroll
    for (int off = 16; off <= 32; off <<= 1) {
        pv0 += __shfl_xor(pv0, off, 64); pq0 += __shfl_xor(pq0, off, 64);
        pv1 += __shfl_xor(pv1, off, 64); pq1 += __shfl_xor(pq1, off, 64);
        pv2 += __shfl_xor(pv2, off, 64); pq2 += __shfl_xor(pq2, off, 64);
        pv3 += __shfl_xor(pv3, off, 64); pq3 += __shfl_xor(pq3, off, 64);
    }
    if (lane < 16) {
        *(float4*)&swave[w][lane * 4] = make_float4(pv0, pv1, pv2, pv3);
        *(float4*)&swave[w][64 + lane * 4] = make_float4(pq0, pq1, pq2, pq3);
    }
    __syncthreads();
    if (tid < 128) {
        float t = swave[0][tid] + swave[1][tid] + swave[2][tid] + swave[3][tid];
        atomicAdd(st1 + (bid & (NCOPY - 1)) * 128 + tid, t);
    }

    // stage w1/b1 now — latency hides under the grid-sync wait
    for (int i = tid; i < EMB * HID; i += 256) w1s[i] = w1[i];
    if (tid < 64) w1s[EMB * HID + tid] = 0.f;
    if (tid < HID) b1s[tid] = b1[tid];

    cg::this_grid().sync();

    // ---------------- P2: BN1 coefficients ----------------
    if (tid < 64) {
        float s = 0, q = 0;
        for (int cc = 0; cc < NCOPY; ++cc) {
            s += st1[cc * 128 + tid];
            q += st1[cc * 128 + 64 + tid];
        }
        float mean = s * (1.f / BATCH);
        float var = q * (1.f / BATCH) - mean * mean;
        float a = g_bi[tid] * rsqrtf(var + 1e-5f);
        c1s[tid] = a;
        c1s[64 + tid] = be_bi[tid] - mean * a;
    }
    __syncthreads();

    // ---------------- P3: FC1 into registers ----------------
    const int l = lane;
    const float a1 = c1s[l], c1v = c1s[64 + l];
    float z[8];
#pragma unroll
    for (int rr = 0; rr < 8; ++rr) {
        float v = sbi[w * 8 + rr][l];
        v = a1 * v + c1v;
        z[rr] = v > 0.f ? v : 0.f;
    }
    float acc[8][4];
#pragma unroll
    for (int rr = 0; rr < 8; ++rr)
#pragma unroll
        for (int k = 0; k < 4; ++k) acc[rr][k] = 0.f;

#pragma unroll 8
    for (int d = 0; d < EMB; ++d) {
        float w0 = w1s[d * HID + l];
        float wv1 = w1s[d * HID + 64 + l];
        float w2 = w1s[d * HID + 128 + l];
        float w3 = w1s[d * HID + 192 + l];  // zero-padded for l>=8
#pragma unroll
        for (int rr = 0; rr < 8; ++rr) {
            float zz = __int_as_float(
                __builtin_amdgcn_readlane(__float_as_int(z[rr]), d));
            acc[rr][0] += zz * w0;
            acc[rr][1] += zz * wv1;
            acc[rr][2] += zz * w2;
            acc[rr][3] += zz * w3;
        }
    }

    float s0 = 0, s1 = 0, s2 = 0, s3 = 0, q0 = 0, q1 = 0, q2 = 0, q3 = 0;
    const float bb0 = b1s[l], bb1 = b1s[64 + l], bb2 = b1s[128 + l];
    const float bb3 = (l < 8) ? b1s[192 + l] : 0.f;
#pragma unroll
    for (int rr = 0; rr < 8; ++rr) {
        acc[rr][0] += bb0; acc[rr][1] += bb1;
        acc[rr][2] += bb2; acc[rr][3] += bb3;
        s0 += acc[rr][0]; q0 += acc[rr][0] * acc[rr][0];
        s1 += acc[rr][1]; q1 += acc[rr][1] * acc[rr][1];
        s2 += acc[rr][2]; q2 += acc[rr][2] * acc[rr][2];
        if (l < 8) { s3 += acc[rr][3]; q3 += acc[rr][3] * acc[rr][3]; }
    }
    {
        float* st = st2 + (bid & (NCOPY - 1)) * 400;
        atomicAdd(st + l, s0);        atomicAdd(st + 200 + l, q0);
        atomicAdd(st + 64 + l, s1);   atomicAdd(st + 200 + 64 + l, q1);
        atomicAdd(st + 128 + l, s2);  atomicAdd(st + 200 + 128 + l, q2);
        if (l < 8) { atomicAdd(st + 192 + l, s3); atomicAdd(st + 200 + 192 + l, q3); }
    }

    cg::this_grid().sync();

    // ---------------- P4: BN2 coefficients ----------------
    if (tid < HID) {
        float s = 0, q = 0;
        for (int cc = 0; cc < NCOPY; ++cc) {
            s += st2[cc * 400 + tid];
            q += st2[cc * 400 + 200 + tid];
        }
        float mean = s * (1.f / BATCH);
        float var = q * (1.f / BATCH) - mean * mean;
        float a = g_h[tid] * rsqrtf(var + 1e-5f);
        c2s[tid] = a;
        c2s[200 + tid] = be_h[tid] - mean * a;
    }
    __syncthreads();

    // ---------------- P5: BN2 + relu + dot(w_last) + sigmoid ----------------
    const int j0 = l, j1 = 64 + l, j2 = 128 + l;
    const int j3 = (l < 8) ? (192 + l) : 199;
    const float A0 = c2s[j0], C0 = c2s[200 + j0];
    const float A1 = c2s[j1], C1 = c2s[200 + j1];
    const float A2 = c2s[j2], C2 = c2s[200 + j2];
    const float A3 = c2s[j3], C3 = c2s[200 + j3];
    const float W0 = wl[j0], W1v = wl[j1], W2 = wl[j2], W3 = wl[j3];
    const float blv = bl[0];

#pragma unroll
    for (int rr = 0; rr < 8; ++rr) {
        float v0 = A0 * acc[rr][0] + C0;
        float v1 = A1 * acc[rr][1] + C1;
        float v2 = A2 * acc[rr][2] + C2;
        float v3 = A3 * acc[rr][3] + C3;
        v0 = v0 > 0.f ? v0 : 0.f;
        v1 = v1 > 0.f ? v1 : 0.f;
        v2 = v2 > 0.f ? v2 : 0.f;
        v3 = v3 > 0.f ? v3 : 0.f;
        float t = v0 * W0 + v1 * W1v + v2 * W2 + ((l < 8) ? v3 * W3 : 0.f);
#pragma unroll
        for (int off = 32; off > 0; off >>= 1) t += __shfl_xor(t, off, 64);
        if (l == 0) out[row0 + w * 8 + rr] = 1.f / (1.f + __expf(-(t + blv)));
    }
}

extern "C" void kernel_launch(void* const* d_in, const int* in_sizes, int n_in,
                              void* d_out, int out_size, void* d_ws, size_t ws_size,
                              hipStream_t stream) {
    const int* x = (const int*)d_in[0];
    const float* emb = (const float*)d_in[1];
    const float* w1 = (const float*)d_in[2];
    const float* b1 = (const float*)d_in[3];
    const float* wl = (const float*)d_in[4];
    const float* bl = (const float*)d_in[5];
    const float* g_bi = (const float*)d_in[6];
    const float* be_bi = (const float*)d_in[7];
    const float* g_h = (const float*)d_in[8];
    const float* be_h = (const float*)d_in[9];
    float* out = (float*)d_out;

    float* st1 = (float*)d_ws;               // 16*128
    float* st2 = st1 + NCOPY * 128;          // 16*400

    hipMemsetAsync(d_ws, 0, (NCOPY * 128 + NCOPY * 400) * sizeof(float), stream);

    void* args[] = {(void*)&x, (void*)&emb, (void*)&w1, (void*)&b1,
                    (void*)&wl, (void*)&bl, (void*)&g_bi, (void*)&be_bi,
                    (void*)&g_h, (void*)&be_h, (void*)&out, (void*)&st1, (void*)&st2};
    hipLaunchCooperativeKernel((void*)k_fused, dim3(GRID), dim3(256), args, 0, stream);
}

// Round 4
// 104.625 us; speedup vs baseline: 1.6517x; 1.6517x over previous
//
#include <hip/hip_runtime.h>
#include <hip/hip_bf16.h>
#include <hip/hip_cooperative_groups.h>

namespace cg = cooperative_groups;

#define BATCH 16384
#define FIELDS 50
#define EMB 64
#define HID 200
#define NC1 32   // st1 replication (gather kernel, 2048 blocks)
#define NC2 16   // st2 replication (tail kernel, 512 blocks)

// ---------------- K_A: gather + FM + BN1 partial stats ---------------------
// 2048 blocks x 256 thr. 8 rows/block; each row split: 16 dim-groups x 2
// field-halves (25 float4 gathers/thread). 32 waves/CU target for max MLP.
__global__ __launch_bounds__(256, 8) void k_fm(const int* __restrict__ x,
                                               const float* __restrict__ emb,
                                               float* __restrict__ bi,
                                               float* __restrict__ st1) {
    __shared__ int sidx[8 * FIELDS];
    __shared__ float swave[4][128];
    const int tid = threadIdx.x;
    const int bid = blockIdx.x;
    for (int i = tid; i < 8 * FIELDS; i += 256)
        sidx[i] = x[bid * 8 * FIELDS + i];
    __syncthreads();

    const int r = tid >> 5;         // row in block 0..7 (2 rows per wave)
    const int h = (tid >> 4) & 1;   // field half: fields h*25 .. h*25+24
    const int c = tid & 15;         // dim group: dims 4c..4c+3
    const int* rowidx = sidx + r * FIELDS + h * 25;

    float s0 = 0, s1 = 0, s2 = 0, s3 = 0, q0 = 0, q1 = 0, q2 = 0, q3 = 0;
#pragma unroll
    for (int f = 0; f < 25; ++f) {
        const float4 v = *(const float4*)(emb + (size_t)rowidx[f] * EMB + c * 4);
        s0 += v.x; q0 += v.x * v.x;
        s1 += v.y; q1 += v.y * v.y;
        s2 += v.z; q2 += v.z * v.z;
        s3 += v.w; q3 += v.w * v.w;
    }
    // combine the two field-halves (lanes 16 apart) -> all lanes hold full s,q
    s0 += __shfl_xor(s0, 16, 64); q0 += __shfl_xor(q0, 16, 64);
    s1 += __shfl_xor(s1, 16, 64); q1 += __shfl_xor(q1, 16, 64);
    s2 += __shfl_xor(s2, 16, 64); q2 += __shfl_xor(q2, 16, 64);
    s3 += __shfl_xor(s3, 16, 64); q3 += __shfl_xor(q3, 16, 64);

    float4 o;
    o.x = 0.5f * (s0 * s0 - q0);
    o.y = 0.5f * (s1 * s1 - q1);
    o.z = 0.5f * (s2 * s2 - q2);
    o.w = 0.5f * (s3 * s3 - q3);
    const int row = bid * 8 + r;
    if (h == 0) *(float4*)(bi + row * EMB + c * 4) = o;

    // BN1 partials: sum o and o^2 over this wave's 2 rows (lanes 32 apart)
    float pv0 = o.x, pv1 = o.y, pv2 = o.z, pv3 = o.w;
    float pq0 = o.x * o.x, pq1 = o.y * o.y, pq2 = o.z * o.z, pq3 = o.w * o.w;
    pv0 += __shfl_xor(pv0, 32, 64); pq0 += __shfl_xor(pq0, 32, 64);
    pv1 += __shfl_xor(pv1, 32, 64); pq1 += __shfl_xor(pq1, 32, 64);
    pv2 += __shfl_xor(pv2, 32, 64); pq2 += __shfl_xor(pq2, 32, 64);
    pv3 += __shfl_xor(pv3, 32, 64); pq3 += __shfl_xor(pq3, 32, 64);

    const int lane = tid & 63;
    const int w = tid >> 6;
    if (lane < 16) {
        *(float4*)&swave[w][lane * 4] = make_float4(pv0, pv1, pv2, pv3);
        *(float4*)&swave[w][64 + lane * 4] = make_float4(pq0, pq1, pq2, pq3);
    }
    __syncthreads();
    if (tid < 128) {
        float t = swave[0][tid] + swave[1][tid] + swave[2][tid] + swave[3][tid];
        atomicAdd(st1 + (bid & (NC1 - 1)) * 128 + tid, t);
    }
}

// ---------------- K_B: BN1 coef + FC1 (regs) + BN2 + out (cooperative) -----
// grid 512 x 256, 2 blocks/CU. y never hits HBM: wave w's acc[rr][k] holds
// y[row0+w*8+rr][k*64+l], exactly the layout the 200-dim output dot needs.
__global__ __launch_bounds__(256, 2) void k_tail(
    const float* __restrict__ bi, const float* __restrict__ st1,
    const float* __restrict__ w1, const float* __restrict__ b1,
    const float* __restrict__ wl, const float* __restrict__ bl,
    const float* __restrict__ g_bi, const float* __restrict__ be_bi,
    const float* __restrict__ g_h, const float* __restrict__ be_h,
    float* __restrict__ out, float* __restrict__ st2)
{
    __shared__ float w1s[EMB * HID + 64];  // zero-padded tail for l>=8 j3 reads
    __shared__ float b1s[HID];
    __shared__ float c1s[128];
    __shared__ float c2s[400];

    const int tid = threadIdx.x;
    const int bid = blockIdx.x;
    const int l = tid & 63;
    const int w = tid >> 6;
    const int row0 = bid * 32;

    for (int i = tid; i < EMB * HID; i += 256) w1s[i] = w1[i];
    if (tid < 64) w1s[EMB * HID + tid] = 0.f;
    if (tid < HID) b1s[tid] = b1[tid];
    if (tid < 64) {
        float s = 0, q = 0;
        for (int cc = 0; cc < NC1; ++cc) {
            s += st1[cc * 128 + tid];
            q += st1[cc * 128 + 64 + tid];
        }
        float mean = s * (1.f / BATCH);
        float var = q * (1.f / BATCH) - mean * mean;
        float a = g_bi[tid] * rsqrtf(var + 1e-5f);
        c1s[tid] = a;
        c1s[64 + tid] = be_bi[tid] - mean * a;
    }
    __syncthreads();

    // ---- FC1 into registers ----
    const float a1 = c1s[l], c1v = c1s[64 + l];
    float z[8];
#pragma unroll
    for (int rr = 0; rr < 8; ++rr) {
        float v = bi[(row0 + w * 8 + rr) * EMB + l];
        v = a1 * v + c1v;
        z[rr] = v > 0.f ? v : 0.f;
    }
    float acc[8][4];
#pragma unroll
    for (int rr = 0; rr < 8; ++rr)
#pragma unroll
        for (int k = 0; k < 4; ++k) acc[rr][k] = 0.f;

#pragma unroll 8
    for (int d = 0; d < EMB; ++d) {
        float w0 = w1s[d * HID + l];
        float wv1 = w1s[d * HID + 64 + l];
        float w2 = w1s[d * HID + 128 + l];
        float w3 = w1s[d * HID + 192 + l];  // zero-padded for l>=8
#pragma unroll
        for (int rr = 0; rr < 8; ++rr) {
            float zz = __int_as_float(
                __builtin_amdgcn_readlane(__float_as_int(z[rr]), d));
            acc[rr][0] += zz * w0;
            acc[rr][1] += zz * wv1;
            acc[rr][2] += zz * w2;
            acc[rr][3] += zz * w3;
        }
    }

    float s0 = 0, s1 = 0, s2 = 0, s3 = 0, q0 = 0, q1 = 0, q2 = 0, q3 = 0;
    const float bb0 = b1s[l], bb1 = b1s[64 + l], bb2 = b1s[128 + l];
    const float bb3 = (l < 8) ? b1s[192 + l] : 0.f;
#pragma unroll
    for (int rr = 0; rr < 8; ++rr) {
        acc[rr][0] += bb0; acc[rr][1] += bb1;
        acc[rr][2] += bb2; acc[rr][3] += bb3;
        s0 += acc[rr][0]; q0 += acc[rr][0] * acc[rr][0];
        s1 += acc[rr][1]; q1 += acc[rr][1] * acc[rr][1];
        s2 += acc[rr][2]; q2 += acc[rr][2] * acc[rr][2];
        if (l < 8) { s3 += acc[rr][3]; q3 += acc[rr][3] * acc[rr][3]; }
    }
    {
        float* st = st2 + (bid & (NC2 - 1)) * 400;
        atomicAdd(st + l, s0);        atomicAdd(st + 200 + l, q0);
        atomicAdd(st + 64 + l, s1);   atomicAdd(st + 200 + 64 + l, q1);
        atomicAdd(st + 128 + l, s2);  atomicAdd(st + 200 + 128 + l, q2);
        if (l < 8) { atomicAdd(st + 192 + l, s3); atomicAdd(st + 200 + 192 + l, q3); }
    }

    cg::this_grid().sync();

    if (tid < HID) {
        float s = 0, q = 0;
        for (int cc = 0; cc < NC2; ++cc) {
            s += st2[cc * 400 + tid];
            q += st2[cc * 400 + 200 + tid];
        }
        float mean = s * (1.f / BATCH);
        float var = q * (1.f / BATCH) - mean * mean;
        float a = g_h[tid] * rsqrtf(var + 1e-5f);
        c2s[tid] = a;
        c2s[200 + tid] = be_h[tid] - mean * a;
    }
    __syncthreads();

    const int j0 = l, j1 = 64 + l, j2 = 128 + l;
    const int j3 = (l < 8) ? (192 + l) : 199;
    const float A0 = c2s[j0], C0 = c2s[200 + j0];
    const float A1 = c2s[j1], C1 = c2s[200 + j1];
    const float A2 = c2s[j2], C2 = c2s[200 + j2];
    const float A3 = c2s[j3], C3 = c2s[200 + j3];
    const float W0 = wl[j0], W1v = wl[j1], W2 = wl[j2], W3 = wl[j3];
    const float blv = bl[0];

#pragma unroll
    for (int rr = 0; rr < 8; ++rr) {
        float v0 = A0 * acc[rr][0] + C0;
        float v1 = A1 * acc[rr][1] + C1;
        float v2 = A2 * acc[rr][2] + C2;
        float v3 = A3 * acc[rr][3] + C3;
        v0 = v0 > 0.f ? v0 : 0.f;
        v1 = v1 > 0.f ? v1 : 0.f;
        v2 = v2 > 0.f ? v2 : 0.f;
        v3 = v3 > 0.f ? v3 : 0.f;
        float t = v0 * W0 + v1 * W1v + v2 * W2 + ((l < 8) ? v3 * W3 : 0.f);
#pragma unroll
        for (int off = 32; off > 0; off >>= 1) t += __shfl_xor(t, off, 64);
        if (l == 0) out[row0 + w * 8 + rr] = 1.f / (1.f + __expf(-(t + blv)));
    }
}

extern "C" void kernel_launch(void* const* d_in, const int* in_sizes, int n_in,
                              void* d_out, int out_size, void* d_ws, size_t ws_size,
                              hipStream_t stream) {
    const int* x = (const int*)d_in[0];
    const float* emb = (const float*)d_in[1];
    const float* w1 = (const float*)d_in[2];
    const float* b1 = (const float*)d_in[3];
    const float* wl = (const float*)d_in[4];
    const float* bl = (const float*)d_in[5];
    const float* g_bi = (const float*)d_in[6];
    const float* be_bi = (const float*)d_in[7];
    const float* g_h = (const float*)d_in[8];
    const float* be_h = (const float*)d_in[9];
    float* out = (float*)d_out;

    float* st1 = (float*)d_ws;               // NC1*128
    float* st2 = st1 + NC1 * 128;            // NC2*400
    float* bi = st2 + NC2 * 400;             // BATCH*64

    hipMemsetAsync(d_ws, 0, (NC1 * 128 + NC2 * 400) * sizeof(float), stream);

    k_fm<<<BATCH / 8, 256, 0, stream>>>(x, emb, bi, st1);

    void* args[] = {(void*)&bi, (void*)&st1, (void*)&w1, (void*)&b1,
                    (void*)&wl, (void*)&bl, (void*)&g_bi, (void*)&be_bi,
                    (void*)&g_h, (void*)&be_h, (void*)&out, (void*)&st2};
    hipLaunchCooperativeKernel((void*)k_tail, dim3(512), dim3(256), args, 0, stream);
}

// Round 5
// 100.264 us; speedup vs baseline: 1.7236x; 1.0435x over previous
//
#include <hip/hip_runtime.h>
#include <hip/hip_bf16.h>
#include <hip/hip_cooperative_groups.h>

namespace cg = cooperative_groups;

#define BATCH 16384
#define FIELDS 50
#define EMB 64
#define HID 200
#define NC1 16   // st1 replication (gather kernel)
#define NC2 16   // st2 replication (tail kernel)

// ---------------- K_A: gather + FM + BN1 partial stats ---------------------
// Round-2 proven structure: 1024 blocks x 256 thr = 16 rows/block; lane
// c=tid&15 owns dims 4c..4c+3 of row tid>>4; 50 float4 gathers per thread.
// No min-waves bound: let the compiler keep ~16 loads in flight.
__global__ __launch_bounds__(256) void k_fm(const int* __restrict__ x,
                                            const float* __restrict__ emb,
                                            float* __restrict__ bi,
                                            float* __restrict__ st1) {
    __shared__ int sidx[16 * FIELDS];
    __shared__ float swave[4][128];
    const int tid = threadIdx.x;
    const int bid = blockIdx.x;
    for (int i = tid; i < 16 * FIELDS; i += 256)
        sidx[i] = x[bid * 16 * FIELDS + i];
    __syncthreads();

    const int r = tid >> 4;   // row within block 0..15
    const int c = tid & 15;   // dim group: dims 4c..4c+3
    const int* rowidx = sidx + r * FIELDS;

    float s0 = 0, s1 = 0, s2 = 0, s3 = 0, q0 = 0, q1 = 0, q2 = 0, q3 = 0;
#pragma unroll 16
    for (int f = 0; f < FIELDS; ++f) {
        const float4 v = *(const float4*)(emb + (size_t)rowidx[f] * EMB + c * 4);
        s0 += v.x; q0 += v.x * v.x;
        s1 += v.y; q1 += v.y * v.y;
        s2 += v.z; q2 += v.z * v.z;
        s3 += v.w; q3 += v.w * v.w;
    }
    float4 o;
    o.x = 0.5f * (s0 * s0 - q0);
    o.y = 0.5f * (s1 * s1 - q1);
    o.z = 0.5f * (s2 * s2 - q2);
    o.w = 0.5f * (s3 * s3 - q3);
    const int row = bid * 16 + r;
    *(float4*)(bi + row * EMB + c * 4) = o;

    // BN1 partial stats over this block's 16 rows
    float pv0 = o.x, pv1 = o.y, pv2 = o.z, pv3 = o.w;
    float pq0 = o.x * o.x, pq1 = o.y * o.y, pq2 = o.z * o.z, pq3 = o.w * o.w;
#pragma unroll
    for (int off = 16; off <= 32; off <<= 1) {
        pv0 += __shfl_xor(pv0, off, 64); pq0 += __shfl_xor(pq0, off, 64);
        pv1 += __shfl_xor(pv1, off, 64); pq1 += __shfl_xor(pq1, off, 64);
        pv2 += __shfl_xor(pv2, off, 64); pq2 += __shfl_xor(pq2, off, 64);
        pv3 += __shfl_xor(pv3, off, 64); pq3 += __shfl_xor(pq3, off, 64);
    }
    const int lane = tid & 63;
    const int w = tid >> 6;
    if (lane < 16) {
        *(float4*)&swave[w][lane * 4] = make_float4(pv0, pv1, pv2, pv3);
        *(float4*)&swave[w][64 + lane * 4] = make_float4(pq0, pq1, pq2, pq3);
    }
    __syncthreads();
    if (tid < 128) {
        float t = swave[0][tid] + swave[1][tid] + swave[2][tid] + swave[3][tid];
        atomicAdd(st1 + (bid & (NC1 - 1)) * 128 + tid, t);
    }
}

// ---------------- K_B: BN1 coef + FC1 (regs) + BN2 + out (cooperative) -----
// grid 512 x 256, 2 blocks/CU. y never hits HBM: wave w's acc[rr][k] holds
// y[row0+w*8+rr][k*64+l], exactly the layout the 200-dim output dot needs.
__global__ __launch_bounds__(256, 2) void k_tail(
    const float* __restrict__ bi, const float* __restrict__ st1,
    const float* __restrict__ w1, const float* __restrict__ b1,
    const float* __restrict__ wl, const float* __restrict__ bl,
    const float* __restrict__ g_bi, const float* __restrict__ be_bi,
    const float* __restrict__ g_h, const float* __restrict__ be_h,
    float* __restrict__ out, float* __restrict__ st2)
{
    __shared__ float w1s[EMB * HID + 64];  // zero-padded tail for l>=8 j3 reads
    __shared__ float b1s[HID];
    __shared__ float c1s[128];
    __shared__ float c2s[400];

    const int tid = threadIdx.x;
    const int bid = blockIdx.x;
    const int l = tid & 63;
    const int w = tid >> 6;
    const int row0 = bid * 32;

    for (int i = tid; i < EMB * HID; i += 256) w1s[i] = w1[i];
    if (tid < 64) w1s[EMB * HID + tid] = 0.f;
    if (tid < HID) b1s[tid] = b1[tid];
    if (tid < 64) {
        float s = 0, q = 0;
        for (int cc = 0; cc < NC1; ++cc) {
            s += st1[cc * 128 + tid];
            q += st1[cc * 128 + 64 + tid];
        }
        float mean = s * (1.f / BATCH);
        float var = q * (1.f / BATCH) - mean * mean;
        float a = g_bi[tid] * rsqrtf(var + 1e-5f);
        c1s[tid] = a;
        c1s[64 + tid] = be_bi[tid] - mean * a;
    }
    __syncthreads();

    // ---- FC1 into registers ----
    const float a1 = c1s[l], c1v = c1s[64 + l];
    float z[8];
#pragma unroll
    for (int rr = 0; rr < 8; ++rr) {
        float v = bi[(row0 + w * 8 + rr) * EMB + l];
        v = a1 * v + c1v;
        z[rr] = v > 0.f ? v : 0.f;
    }
    float acc[8][4];
#pragma unroll
    for (int rr = 0; rr < 8; ++rr)
#pragma unroll
        for (int k = 0; k < 4; ++k) acc[rr][k] = 0.f;

#pragma unroll 8
    for (int d = 0; d < EMB; ++d) {
        float w0 = w1s[d * HID + l];
        float wv1 = w1s[d * HID + 64 + l];
        float w2 = w1s[d * HID + 128 + l];
        float w3 = w1s[d * HID + 192 + l];  // zero-padded for l>=8
#pragma unroll
        for (int rr = 0; rr < 8; ++rr) {
            float zz = __int_as_float(
                __builtin_amdgcn_readlane(__float_as_int(z[rr]), d));
            acc[rr][0] += zz * w0;
            acc[rr][1] += zz * wv1;
            acc[rr][2] += zz * w2;
            acc[rr][3] += zz * w3;
        }
    }

    float s0 = 0, s1 = 0, s2 = 0, s3 = 0, q0 = 0, q1 = 0, q2 = 0, q3 = 0;
    const float bb0 = b1s[l], bb1 = b1s[64 + l], bb2 = b1s[128 + l];
    const float bb3 = (l < 8) ? b1s[192 + l] : 0.f;
#pragma unroll
    for (int rr = 0; rr < 8; ++rr) {
        acc[rr][0] += bb0; acc[rr][1] += bb1;
        acc[rr][2] += bb2; acc[rr][3] += bb3;
        s0 += acc[rr][0]; q0 += acc[rr][0] * acc[rr][0];
        s1 += acc[rr][1]; q1 += acc[rr][1] * acc[rr][1];
        s2 += acc[rr][2]; q2 += acc[rr][2] * acc[rr][2];
        if (l < 8) { s3 += acc[rr][3]; q3 += acc[rr][3] * acc[rr][3]; }
    }
    {
        float* st = st2 + (bid & (NC2 - 1)) * 400;
        atomicAdd(st + l, s0);        atomicAdd(st + 200 + l, q0);
        atomicAdd(st + 64 + l, s1);   atomicAdd(st + 200 + 64 + l, q1);
        atomicAdd(st + 128 + l, s2);  atomicAdd(st + 200 + 128 + l, q2);
        if (l < 8) { atomicAdd(st + 192 + l, s3); atomicAdd(st + 200 + 192 + l, q3); }
    }

    cg::this_grid().sync();

    if (tid < HID) {
        float s = 0, q = 0;
        for (int cc = 0; cc < NC2; ++cc) {
            s += st2[cc * 400 + tid];
            q += st2[cc * 400 + 200 + tid];
        }
        float mean = s * (1.f / BATCH);
        float var = q * (1.f / BATCH) - mean * mean;
        float a = g_h[tid] * rsqrtf(var + 1e-5f);
        c2s[tid] = a;
        c2s[200 + tid] = be_h[tid] - mean * a;
    }
    __syncthreads();

    const int j0 = l, j1 = 64 + l, j2 = 128 + l;
    const int j3 = (l < 8) ? (192 + l) : 199;
    const float A0 = c2s[j0], C0 = c2s[200 + j0];
    const float A1 = c2s[j1], C1 = c2s[200 + j1];
    const float A2 = c2s[j2], C2 = c2s[200 + j2];
    const float A3 = c2s[j3], C3 = c2s[200 + j3];
    const float W0 = wl[j0], W1v = wl[j1], W2 = wl[j2], W3 = wl[j3];
    const float blv = bl[0];

#pragma unroll
    for (int rr = 0; rr < 8; ++rr) {
        float v0 = A0 * acc[rr][0] + C0;
        float v1 = A1 * acc[rr][1] + C1;
        float v2 = A2 * acc[rr][2] + C2;
        float v3 = A3 * acc[rr][3] + C3;
        v0 = v0 > 0.f ? v0 : 0.f;
        v1 = v1 > 0.f ? v1 : 0.f;
        v2 = v2 > 0.f ? v2 : 0.f;
        v3 = v3 > 0.f ? v3 : 0.f;
        float t = v0 * W0 + v1 * W1v + v2 * W2 + ((l < 8) ? v3 * W3 : 0.f);
#pragma unroll
        for (int off = 32; off > 0; off >>= 1) t += __shfl_xor(t, off, 64);
        if (l == 0) out[row0 + w * 8 + rr] = 1.f / (1.f + __expf(-(t + blv)));
    }
}

extern "C" void kernel_launch(void* const* d_in, const int* in_sizes, int n_in,
                              void* d_out, int out_size, void* d_ws, size_t ws_size,
                              hipStream_t stream) {
    const int* x = (const int*)d_in[0];
    const float* emb = (const float*)d_in[1];
    const float* w1 = (const float*)d_in[2];
    const float* b1 = (const float*)d_in[3];
    const float* wl = (const float*)d_in[4];
    const float* bl = (const float*)d_in[5];
    const float* g_bi = (const float*)d_in[6];
    const float* be_bi = (const float*)d_in[7];
    const float* g_h = (const float*)d_in[8];
    const float* be_h = (const float*)d_in[9];
    float* out = (float*)d_out;

    float* st1 = (float*)d_ws;               // NC1*128
    float* st2 = st1 + NC1 * 128;            // NC2*400
    float* bi = st2 + NC2 * 400;             // BATCH*64

    hipMemsetAsync(d_ws, 0, (NC1 * 128 + NC2 * 400) * sizeof(float), stream);

    k_fm<<<BATCH / 16, 256, 0, stream>>>(x, emb, bi, st1);

    void* args[] = {(void*)&bi, (void*)&st1, (void*)&w1, (void*)&b1,
                    (void*)&wl, (void*)&bl, (void*)&g_bi, (void*)&be_bi,
                    (void*)&g_h, (void*)&be_h, (void*)&out, (void*)&st2};
    hipLaunchCooperativeKernel((void*)k_tail, dim3(512), dim3(256), args, 0, stream);
}

// Round 6
// 68.142 us; speedup vs baseline: 2.5361x; 1.4714x over previous
//
#include <hip/hip_runtime.h>
#include <hip/hip_bf16.h>

#define BATCH 16384
#define FIELDS 50
#define EMB 64
#define HID 200
#define NCOPY 16

// ---------------- K1: gather + FM bi-interaction + partial column stats ----
// 256 threads = 16 rows/block; lane c=tid&15 owns dims 4c..4c+3 of row tid>>4.
// 50 float4 gathers/thread, unroll 10 (proven best: ~110 VGPR, 16 waves/CU).
// Gather is memory-service-bound at ~4.2 TB/s logical — decomposition-invariant.
__global__ __launch_bounds__(256) void k_fm(const int* __restrict__ x,
                                            const float* __restrict__ emb,
                                            float* __restrict__ bi,
                                            float* __restrict__ st1) {
    __shared__ int sidx[16 * FIELDS];
    __shared__ float swave[4][128];
    const int tid = threadIdx.x;
    const int bid = blockIdx.x;
    for (int i = tid; i < 16 * FIELDS; i += 256)
        sidx[i] = x[bid * 16 * FIELDS + i];
    __syncthreads();

    const int r = tid >> 4;   // row within block 0..15
    const int c = tid & 15;   // dim group: dims 4c..4c+3
    const int* rowidx = sidx + r * FIELDS;

    float s0 = 0, s1 = 0, s2 = 0, s3 = 0, q0 = 0, q1 = 0, q2 = 0, q3 = 0;
#pragma unroll 10
    for (int f = 0; f < FIELDS; ++f) {
        const float4 v = *(const float4*)(emb + (size_t)rowidx[f] * EMB + c * 4);
        s0 += v.x; q0 += v.x * v.x;
        s1 += v.y; q1 += v.y * v.y;
        s2 += v.z; q2 += v.z * v.z;
        s3 += v.w; q3 += v.w * v.w;
    }
    float4 o;
    o.x = 0.5f * (s0 * s0 - q0);
    o.y = 0.5f * (s1 * s1 - q1);
    o.z = 0.5f * (s2 * s2 - q2);
    o.w = 0.5f * (s3 * s3 - q3);
    const int row = bid * 16 + r;
    *(float4*)(bi + row * EMB + c * 4) = o;

    // BN1 partial stats over this block's 16 rows
    float pv0 = o.x, pv1 = o.y, pv2 = o.z, pv3 = o.w;
    float pq0 = o.x * o.x, pq1 = o.y * o.y, pq2 = o.z * o.z, pq3 = o.w * o.w;
#pragma unroll
    for (int off = 16; off <= 32; off <<= 1) {
        pv0 += __shfl_xor(pv0, off, 64); pq0 += __shfl_xor(pq0, off, 64);
        pv1 += __shfl_xor(pv1, off, 64); pq1 += __shfl_xor(pq1, off, 64);
        pv2 += __shfl_xor(pv2, off, 64); pq2 += __shfl_xor(pq2, off, 64);
        pv3 += __shfl_xor(pv3, off, 64); pq3 += __shfl_xor(pq3, off, 64);
    }
    const int lane = tid & 63;
    const int w = tid >> 6;
    if (lane < 16) {
        *(float4*)&swave[w][lane * 4] = make_float4(pv0, pv1, pv2, pv3);
        *(float4*)&swave[w][64 + lane * 4] = make_float4(pq0, pq1, pq2, pq3);
    }
    __syncthreads();
    if (tid < 128) {
        float t = swave[0][tid] + swave[1][tid] + swave[2][tid] + swave[3][tid];
        atomicAdd(st1 + (bid & (NCOPY - 1)) * 128 + tid, t);
    }
}

// ---------------- K3: h1 = relu(BN1(bi)) @ W1 + b1, + partial stats --------
// BN1 coefficient finalization folded in. w1 staged via float4 (3200 dwordx4).
__global__ __launch_bounds__(256) void k_fc1(const float* __restrict__ bi,
                                             const float* __restrict__ st1,
                                             const float* __restrict__ g_bi,
                                             const float* __restrict__ be_bi,
                                             const float* __restrict__ w1,
                                             const float* __restrict__ b1,
                                             float* __restrict__ y,
                                             float* __restrict__ st2) {
    __shared__ float4 w1s4[(EMB * HID + 64) / 4];  // padded tail, 16B aligned
    __shared__ float b1s[HID];
    __shared__ float c1s[128];
    float* w1s = (float*)w1s4;
    const int tid = threadIdx.x;
    for (int i = tid; i < EMB * HID / 4; i += 256)
        w1s4[i] = ((const float4*)w1)[i];
    if (tid < 16) w1s4[EMB * HID / 4 + tid] = make_float4(0.f, 0.f, 0.f, 0.f);
    if (tid < HID) b1s[tid] = b1[tid];
    if (tid < 64) {
        float s = 0.f, q = 0.f;
        for (int cc = 0; cc < NCOPY; ++cc) {
            s += st1[cc * 128 + tid];
            q += st1[cc * 128 + 64 + tid];
        }
        float mean = s * (1.f / BATCH);
        float var = q * (1.f / BATCH) - mean * mean;
        float a = g_bi[tid] * rsqrtf(var + 1e-5f);
        c1s[tid] = a;
        c1s[64 + tid] = be_bi[tid] - mean * a;
    }
    __syncthreads();

    const int l = tid & 63;
    const int w = tid >> 6;
    const float a1 = c1s[l];
    const float c1v = c1s[64 + l];
    const int base_row = blockIdx.x * 32 + w * 8;

    float z[8];
#pragma unroll
    for (int r = 0; r < 8; ++r) {
        float v = bi[(base_row + r) * EMB + l];
        v = a1 * v + c1v;
        z[r] = v > 0.f ? v : 0.f;
    }

    float acc[8][4];
#pragma unroll
    for (int r = 0; r < 8; ++r)
#pragma unroll
        for (int k = 0; k < 4; ++k) acc[r][k] = 0.f;

#pragma unroll 8
    for (int d = 0; d < EMB; ++d) {
        float w0 = w1s[d * HID + l];
        float wv1 = w1s[d * HID + 64 + l];
        float w2 = w1s[d * HID + 128 + l];
        float w3 = w1s[d * HID + 192 + l];  // zero-padded for l>=8
#pragma unroll
        for (int r = 0; r < 8; ++r) {
            float zz = __int_as_float(
                __builtin_amdgcn_readlane(__float_as_int(z[r]), d));
            acc[r][0] += zz * w0;
            acc[r][1] += zz * wv1;
            acc[r][2] += zz * w2;
            acc[r][3] += zz * w3;
        }
    }

    float s0 = 0, s1 = 0, s2 = 0, s3 = 0, q0 = 0, q1 = 0, q2 = 0, q3 = 0;
    const float bb0 = b1s[l], bb1 = b1s[64 + l], bb2 = b1s[128 + l];
    const float bb3 = (l < 8) ? b1s[192 + l] : 0.f;
#pragma unroll
    for (int r = 0; r < 8; ++r) {
        int row = base_row + r;
        float v0 = acc[r][0] + bb0;
        float v1 = acc[r][1] + bb1;
        float v2 = acc[r][2] + bb2;
        y[row * HID + l] = v0;
        y[row * HID + 64 + l] = v1;
        y[row * HID + 128 + l] = v2;
        s0 += v0; q0 += v0 * v0;
        s1 += v1; q1 += v1 * v1;
        s2 += v2; q2 += v2 * v2;
        if (l < 8) {
            float v3 = acc[r][3] + bb3;
            y[row * HID + 192 + l] = v3;
            s3 += v3; q3 += v3 * v3;
        }
    }
    float* st = st2 + (blockIdx.x & (NCOPY - 1)) * 400;
    atomicAdd(st + l, s0);
    atomicAdd(st + 200 + l, q0);
    atomicAdd(st + 64 + l, s1);
    atomicAdd(st + 200 + 64 + l, q1);
    atomicAdd(st + 128 + l, s2);
    atomicAdd(st + 200 + 128 + l, q2);
    if (l < 8) {
        atomicAdd(st + 192 + l, s3);
        atomicAdd(st + 200 + 192 + l, q3);
    }
}

// ---------------- K5: out = sigmoid(relu(BN2(y)) @ w_last + b_last) --------
__global__ __launch_bounds__(256) void k_out(const float* __restrict__ y,
                                             const float* __restrict__ st2,
                                             const float* __restrict__ g_h,
                                             const float* __restrict__ be_h,
                                             const float* __restrict__ wl,
                                             const float* __restrict__ bl,
                                             float* __restrict__ out) {
    __shared__ float c2s[400];
    const int tid = threadIdx.x;
    if (tid < HID) {
        float s = 0.f, q = 0.f;
        for (int cc = 0; cc < NCOPY; ++cc) {
            s += st2[cc * 400 + tid];
            q += st2[cc * 400 + 200 + tid];
        }
        float mean = s * (1.f / BATCH);
        float var = q * (1.f / BATCH) - mean * mean;
        float a = g_h[tid] * rsqrtf(var + 1e-5f);
        c2s[tid] = a;
        c2s[200 + tid] = be_h[tid] - mean * a;
    }
    __syncthreads();

    const int l = tid & 63;
    const int w = tid >> 6;
    const int j0 = l, j1 = 64 + l, j2 = 128 + l;
    const int j3 = (l < 8) ? (192 + l) : 199;  // clamped for safety
    const float a0 = c2s[j0], c0 = c2s[200 + j0];
    const float a1 = c2s[j1], c1 = c2s[200 + j1];
    const float a2 = c2s[j2], c2 = c2s[200 + j2];
    const float a3 = c2s[j3], c3 = c2s[200 + j3];
    const float w0 = wl[j0], w1v = wl[j1], w2 = wl[j2], w3 = wl[j3];
    const float blv = bl[0];

#pragma unroll
    for (int it = 0; it < 4; ++it) {
        int row = blockIdx.x * 16 + it * 4 + w;
        const float* yr = y + row * HID;
        float v0 = a0 * yr[j0] + c0;
        float v1 = a1 * yr[j1] + c1;
        float v2 = a2 * yr[j2] + c2;
        float v3 = a3 * yr[j3] + c3;
        v0 = v0 > 0.f ? v0 : 0.f;
        v1 = v1 > 0.f ? v1 : 0.f;
        v2 = v2 > 0.f ? v2 : 0.f;
        v3 = v3 > 0.f ? v3 : 0.f;
        float t = v0 * w0 + v1 * w1v + v2 * w2 + ((l < 8) ? v3 * w3 : 0.f);
#pragma unroll
        for (int off = 32; off > 0; off >>= 1) t += __shfl_xor(t, off, 64);
        if (l == 0) out[row] = 1.f / (1.f + __expf(-(t + blv)));
    }
}

extern "C" void kernel_launch(void* const* d_in, const int* in_sizes, int n_in,
                              void* d_out, int out_size, void* d_ws, size_t ws_size,
                              hipStream_t stream) {
    const int* x = (const int*)d_in[0];
    const float* emb = (const float*)d_in[1];
    const float* w1 = (const float*)d_in[2];
    const float* b1 = (const float*)d_in[3];
    const float* wl = (const float*)d_in[4];
    const float* bl = (const float*)d_in[5];
    const float* g_bi = (const float*)d_in[6];
    const float* be_bi = (const float*)d_in[7];
    const float* g_h = (const float*)d_in[8];
    const float* be_h = (const float*)d_in[9];
    float* out = (float*)d_out;

    float* ws = (float*)d_ws;
    float* bi = ws;                          // BATCH*64
    float* y = bi + BATCH * EMB;             // BATCH*200
    float* st1 = y + (size_t)BATCH * HID;    // 16*128
    float* st2 = st1 + NCOPY * 128;          // 16*400

    hipMemsetAsync(st1, 0, (NCOPY * 128 + NCOPY * 400) * sizeof(float), stream);

    k_fm<<<BATCH / 16, 256, 0, stream>>>(x, emb, bi, st1);
    k_fc1<<<BATCH / 32, 256, 0, stream>>>(bi, st1, g_bi, be_bi, w1, b1, y, st2);
    k_out<<<BATCH / 16, 256, 0, stream>>>(y, st2, g_h, be_h, wl, bl, out);
}